// Round 5
// baseline (568.883 us; speedup 1.0000x reference)
//
#include <hip/hip_runtime.h>

// Problem constants (from reference): B=2048, IN=256, OUT=256
#define BATCH 2048
#define IN_DIM 256
#define OUT_DIM 256
#define BPC 64   // batch elements per block (chunk)

typedef float f32x4 __attribute__((ext_vector_type(4)));

// Block = 256 threads = 4 waves. Wave w owns output row o = otile*4 + w.
// Lane l owns inputs i = 4l..4l+3 (64 lanes * 4 = 256 = IN_DIM).
// W,C precomputed into registers once per block, reused for BPC batches.
__global__ __launch_bounds__(256) void kan_symbolic_kernel(
    const float* __restrict__ x,       // [B, IN]
    const float* __restrict__ affine,  // [OUT, IN, 4]
    const float* __restrict__ mask,    // [OUT, IN]
    float* __restrict__ y,             // [B, OUT]
    float* __restrict__ post)          // [B, OUT, IN]
{
    const int tid  = threadIdx.x;
    const int lane = tid & 63;
    const int wave = tid >> 6;
    const int otile = blockIdx.x & 63;       // 64 o-tiles
    const int chunk = blockIdx.x >> 6;       // 32 batch chunks
    const int o  = otile * 4 + wave;
    const int i0 = lane * 4;

    // ---- Precompute W = mask*a2*a0, C = mask*(a2*a1 + a3) for this (o, i0..i0+3) ----
    // affine[o][i][0..3]: 16 contiguous floats per lane -> 4x f32x4 loads.
    const f32x4* aff = reinterpret_cast<const f32x4*>(
        affine + ((size_t)o * IN_DIM + i0) * 4);
    f32x4 e0 = aff[0];
    f32x4 e1 = aff[1];
    f32x4 e2 = aff[2];
    f32x4 e3 = aff[3];
    f32x4 m = *reinterpret_cast<const f32x4*>(mask + (size_t)o * IN_DIM + i0);

    f32x4 W, C;
    W.x = m.x * e0.z * e0.x;  C.x = m.x * fmaf(e0.z, e0.y, e0.w);
    W.y = m.y * e1.z * e1.x;  C.y = m.y * fmaf(e1.z, e1.y, e1.w);
    W.z = m.z * e2.z * e2.x;  C.z = m.z * fmaf(e2.z, e2.y, e2.w);
    W.w = m.w * e3.z * e3.x;  C.w = m.w * fmaf(e3.z, e3.y, e3.w);

    // ---- Stream over the batch chunk ----
    const int b0 = chunk * BPC;
    for (int b = b0; b < b0 + BPC; ++b) {
        f32x4 x4 = *reinterpret_cast<const f32x4*>(x + (size_t)b * IN_DIM + i0);
        f32x4 p;
        p.x = fmaf(W.x, x4.x, C.x);
        p.y = fmaf(W.y, x4.y, C.y);
        p.z = fmaf(W.z, x4.z, C.z);
        p.w = fmaf(W.w, x4.w, C.w);

        // postacts store: wave writes 64 lanes * 16B = 1 KiB contiguous.
        __builtin_nontemporal_store(p, reinterpret_cast<f32x4*>(
            post + ((size_t)b * OUT_DIM + o) * IN_DIM + i0));

        // y[b][o] = sum_i p  (butterfly reduce over the 64-lane wave)
        float s = (p.x + p.y) + (p.z + p.w);
        #pragma unroll
        for (int off = 1; off < 64; off <<= 1)
            s += __shfl_xor(s, off, 64);
        if (lane == 0)
            y[(size_t)b * OUT_DIM + o] = s;
    }
}

extern "C" void kernel_launch(void* const* d_in, const int* in_sizes, int n_in,
                              void* d_out, int out_size, void* d_ws, size_t ws_size,
                              hipStream_t stream) {
    const float* x      = (const float*)d_in[0];
    const float* affine = (const float*)d_in[1];
    const float* mask   = (const float*)d_in[2];

    float* y    = (float*)d_out;                       // [B, OUT] first
    float* post = y + (size_t)BATCH * OUT_DIM;         // then [B, OUT, IN]

    dim3 grid(64 * (BATCH / BPC));   // 64 o-tiles * 32 chunks = 2048 blocks
    dim3 block(256);
    kan_symbolic_kernel<<<grid, block, 0, stream>>>(x, affine, mask, y, post);
}